// Round 2
// baseline (5573.223 us; speedup 1.0000x reference)
//
// EpisodicMemory: fp32 inputs/output.
//   prep_w    : one-shot fp32->bf16 conversion of fc1_w, W_ih, W_hh into ws.
//   g_kernel  : per-b block, feat@fc1w^T via 16x16x32 bf16 MFMA (unchanged).
//   scan_all  : R6 — persistent kernel, NORMAL launch (R5's hipLaunchCooperativeKernel
//               silently failed: out never written -> absmax = max|ref|). Grid sync is
//               a hand-rolled sense-reversing barrier in __device__ globals:
//               __threadfence (agent release, L2 writeback) -> syncthreads -> thread0
//               relaxed agent fetch_add arrive; last arriver resets cnt + RELEASE-bumps
//               gen; others spin on relaxed agent load -> syncthreads -> __threadfence
//               (acquire, invalidate). cnt self-resets; gen never needs reset -> safe
//               across graph replays. 256 blocks x 256 thr, 141 KB LDS => exactly
//               1 block/CU on 256 CUs (co-residency by construction).
//               Whh slice LDS-resident across all 64 steps; register prefetch of
//               next-kc C/h/Wih under the MFMA phase; next-step C/Wih prefetched
//               before the barrier (fence drains them -> ready at exit). h carried
//               bf16 hi+lo double-buffered in global. hold captured from staged LDS
//               h-tile. XCD-aware block map: XCD x owns b-tiles {2x,2x+1}.
#include <hip/hip_runtime.h>
#include <hip/hip_bf16.h>

#define H_ 512
#define SH_ 120
#define B_ 1024
#define S_ 64

typedef __bf16 bf16x8 __attribute__((ext_vector_type(8)));
typedef float floatx4 __attribute__((ext_vector_type(4)));

__device__ __forceinline__ float bf2f(ushort u) {
    union { unsigned int i; float f; } v; v.i = ((unsigned int)u) << 16; return v.f;
}
__device__ __forceinline__ ushort f2bf(float f) {
    union { float f; unsigned int i; } v; v.f = f;
    unsigned int x = v.i;
    unsigned int r = (x + 0x7fffu + ((x >> 16) & 1u)) >> 16;  // RNE
    return (ushort)r;
}

// --- device-scope grid barrier state (persists across launches; cnt self-resets,
// --- gen is a free-running generation counter so no reset is ever needed) ---
__device__ unsigned g_bar_cnt = 0u;
__device__ unsigned g_bar_gen = 0u;

__device__ __forceinline__ void grid_barrier_256(int tid) {
    __threadfence();                       // release: flush this thread's writes (L2 wb)
    __syncthreads();
    if (tid == 0) {
        const unsigned g = __hip_atomic_load(&g_bar_gen, __ATOMIC_RELAXED,
                                             __HIP_MEMORY_SCOPE_AGENT);
        const unsigned a = __hip_atomic_fetch_add(&g_bar_cnt, 1u, __ATOMIC_ACQ_REL,
                                                  __HIP_MEMORY_SCOPE_AGENT);
        if (a == 255u) {
            __hip_atomic_store(&g_bar_cnt, 0u, __ATOMIC_RELAXED,
                               __HIP_MEMORY_SCOPE_AGENT);
            __hip_atomic_fetch_add(&g_bar_gen, 1u, __ATOMIC_RELEASE,
                                   __HIP_MEMORY_SCOPE_AGENT);  // orders cnt reset first
        } else {
            while (__hip_atomic_load(&g_bar_gen, __ATOMIC_RELAXED,
                                     __HIP_MEMORY_SCOPE_AGENT) == g) {
                __builtin_amdgcn_s_sleep(2);
            }
        }
    }
    __syncthreads();
    __threadfence();                       // acquire: invalidate stale L1/L2
}

// ---------------------------------------------------------------------------
// prep_w: one-shot fp32 -> bf16 of the three weight matrices.
// ---------------------------------------------------------------------------
__global__ __launch_bounds__(256) void prep_w(
    const float* __restrict__ fc1w, ushort* __restrict__ fc1wb,
    const float* __restrict__ Wih,  ushort* __restrict__ Wihb,
    const float* __restrict__ Whh,  ushort* __restrict__ Whhb)
{
    const int stride = gridDim.x * blockDim.x;
    const int tid = blockIdx.x * blockDim.x + threadIdx.x;
    for (int i = tid; i < 61440; i += stride) {            // 120*2048/4
        const float4 v = ((const float4*)fc1w)[i];
        ushort4 o; o.x = f2bf(v.x); o.y = f2bf(v.y); o.z = f2bf(v.z); o.w = f2bf(v.w);
        ((ushort4*)fc1wb)[i] = o;
    }
    for (int i = tid; i < 196608; i += stride) {           // 1536*512/4
        const float4 v = ((const float4*)Wih)[i];
        ushort4 o; o.x = f2bf(v.x); o.y = f2bf(v.y); o.z = f2bf(v.z); o.w = f2bf(v.w);
        ((ushort4*)Wihb)[i] = o;
    }
    for (int i = tid; i < 196608; i += stride) {
        const float4 v = ((const float4*)Whh)[i];
        ushort4 o; o.x = f2bf(v.x); o.y = f2bf(v.y); o.z = f2bf(v.z); o.w = f2bf(v.w);
        ((ushort4*)Whhb)[i] = o;
    }
}

// ---------------------------------------------------------------------------
// G kernel: one block per b. Computes G[b, s] for s=0..63. (unchanged)
// ---------------------------------------------------------------------------
__global__ __launch_bounds__(256) void g_kernel(
    const float* __restrict__ C, const float* __restrict__ Q,
    const float* __restrict__ M, const ushort* __restrict__ fc1wb,
    const float* __restrict__ fc1b, const float* __restrict__ fc2w,
    const float* __restrict__ fc2b, float* __restrict__ G)
{
    __shared__ float qrow[H_];
    __shared__ float mrow[H_];
    __shared__ __align__(16) ushort featT[64 * 72];   // 64 s-rows x 64 k (stride 72)
    __shared__ __align__(16) ushort wT[128 * 72];     // 128 n-rows x 64 k (rows>=120 zero)
    __shared__ float h1s[64 * 132];                   // 64 x 128 fp32 (stride 132)

    const int b = blockIdx.x;
    const int t = threadIdx.x;
    for (int i = t; i < H_; i += 256) { qrow[i] = Q[(size_t)b * H_ + i]; mrow[i] = M[(size_t)b * H_ + i]; }

    const int wrow = t >> 1;
    const int wc0  = (t & 1) * 32;
    if (wrow >= SH_) {              // zero-fill dead wT rows once
        uint4* dst = (uint4*)&wT[wrow * 72 + wc0];
        const uint4 z = {0u, 0u, 0u, 0u};
        dst[0] = z; dst[1] = z; dst[2] = z; dst[3] = z;
    }
    __syncthreads();

    const int lane = t & 63;
    const int wv   = t >> 6;
    const int quad = lane >> 4;
    const int l15  = lane & 15;
    const int arow = wv * 16 + l15;
    const int s    = t >> 2;
    const int c0   = (t & 3) * 16;

    floatx4 acc[8];
#pragma unroll
    for (int i = 0; i < 8; ++i) acc[i] = (floatx4){0.f, 0.f, 0.f, 0.f};

    for (int hc = 0; hc < H_; hc += 64) {
        float cr[16];
        {
            const float4* csrc = (const float4*)(C + ((size_t)b * S_ + s) * H_ + hc + c0);
            *(float4*)&cr[0]  = csrc[0];
            *(float4*)&cr[4]  = csrc[1];
            *(float4*)&cr[8]  = csrc[2];
            *(float4*)&cr[12] = csrc[3];
        }
#pragma unroll
        for (int seg = 0; seg < 4; ++seg) {
#pragma unroll
            for (int u = 0; u < 16; ++u) {
                const int kk = c0 + u;
                const float c = cr[u];
                const float o = (seg == 0 || seg == 2) ? qrow[hc + kk] : mrow[hc + kk];
                const float v = (seg < 2) ? c * o : fabsf(c - o);
                featT[s * 72 + kk] = f2bf(v);
            }
            if (wrow < SH_) {
                const uint4* src = (const uint4*)(fc1wb + (size_t)wrow * (4 * H_) + seg * H_ + hc + wc0);
                uint4* dst = (uint4*)&wT[wrow * 72 + wc0];
                dst[0] = src[0]; dst[1] = src[1]; dst[2] = src[2]; dst[3] = src[3];
            }
            __syncthreads();
#pragma unroll
            for (int ks = 0; ks < 64; ks += 32) {
                const int ao = ks + quad * 8;
                const bf16x8 af = *(const bf16x8*)&featT[arow * 72 + ao];
#pragma unroll
                for (int nt = 0; nt < 8; ++nt) {
                    const bf16x8 bfr = *(const bf16x8*)&wT[(nt * 16 + l15) * 72 + ao];
                    acc[nt] = __builtin_amdgcn_mfma_f32_16x16x32_bf16(af, bfr, acc[nt], 0, 0, 0);
                }
            }
            __syncthreads();
        }
    }

#pragma unroll
    for (int nt = 0; nt < 8; ++nt) {
        const int col = nt * 16 + l15;
        const float bias = (col < SH_) ? fc1b[col] : 0.f;
#pragma unroll
        for (int r = 0; r < 4; ++r) {
            const int row = wv * 16 + quad * 4 + r;
            h1s[row * 132 + col] = (col < SH_) ? tanhf(acc[nt][r] + bias) : 0.f;
        }
    }
    __syncthreads();
    {
        const int part = t & 3;
        float sum = 0.f;
        for (int k = part; k < SH_; k += 4) sum += h1s[s * 132 + k] * fc2w[k];
        sum += __shfl_xor(sum, 1);
        sum += __shfl_xor(sum, 2);
        if (part == 0) {
            const float logit = sum + fc2b[0];
            G[(size_t)b * S_ + s] = 1.f / (1.f + expf(-logit));
        }
    }
}

// ---------------------------------------------------------------------------
// scan_all: persistent scan, normal launch. 256 blocks x 256 threads, 1 block/CU
// (forced by 141 KB LDS). Block = (j-tile 32 cols) x (b-tile 64 batches). Whh
// slice lives in LDS for all 64 steps. Custom grid barrier between steps
// (h double-buffered in global ws).
// ---------------------------------------------------------------------------
__global__ __launch_bounds__(256) void scan_all(
    const float* __restrict__ C, const ushort* __restrict__ Wihb,
    const ushort* __restrict__ Whhb, const float* __restrict__ bih,
    const float* __restrict__ bhh, const float* __restrict__ G,
    ushort* __restrict__ hhi0, ushort* __restrict__ hlo0,
    ushort* __restrict__ hhi1, ushort* __restrict__ hlo1,
    float* __restrict__ out)
{
    __shared__ __align__(16) ushort Whh_s[96 * 520];   // 99840 B, persistent
    __shared__ __align__(16) ushort As[3 * 64 * 72];   // c | h_hi | h_lo  27648 B
    __shared__ __align__(16) ushort Wih_s[96 * 72];    // per-kc staging   13824 B

    const int bx = blockIdx.x;
    // XCD-aware map: XCD x (= bx%8) owns b-tiles {2x, 2x+1} for ALL j-tiles ->
    // per-step C/h slices for its 128 batches stay in that XCD's L2.
    const int jt = bx >> 4;
    const int bt = ((bx & 7) << 1) | ((bx >> 3) & 1);
    const int jb = jt * 32;
    const int bb = bt * 64;
    const int t  = threadIdx.x;
    const int lane = t & 63;
    const int wv   = t >> 6;
    const int quad = lane >> 4;
    const int l15  = lane & 15;
    const int arow = wv * 16 + l15;
    const int crow = t >> 2;
    const int cc0  = (t & 3) * 16;

    // --- one-time: Whh slice (3 gates x 32 j-cols, full K) into LDS ---
#pragma unroll
    for (int i = 0; i < 24; ++i) {
        const int gid = i * 256 + t;          // 0..6143
        const int row = gid >> 6;             // 0..95
        const int grp = gid & 63;             // 0..63 (8-elem groups)
        const int grow = (row >> 5) * H_ + jb + (row & 31);
        *(uint4*)&Whh_s[row * 520 + grp * 8] =
            *(const uint4*)(Whhb + (size_t)grow * H_ + grp * 8);
    }

    // --- hoisted biases (constant across t) ---
    float br_[2], bz_[2], bxn_[2], bhn_[2];
#pragma unroll
    for (int nt = 0; nt < 2; ++nt) {
        const int j = jb + nt * 16 + l15;
        br_[nt]  = bih[j] + bhh[j];
        bz_[nt]  = bih[H_ + j] + bhh[H_ + j];
        bxn_[nt] = bih[2 * H_ + j];
        bhn_[nt] = bhh[2 * H_ + j];
    }

    const int hold_kc  = (jb >> 6) << 6;   // kc chunk containing this block's j cols
    const int hold_off = jb & 63;

    const ushort* hr_hi = hhi0; const ushort* hr_lo = hlo0;
    ushort* hw_hi = hhi1; ushort* hw_lo = hlo1;

    // --- prefetch registers ---
    float cr[16];
    uint4 hreg[4];
    uint4 wreg[3];

    auto load_cw = [&](int tstep, int kc) {
        const float4* src = (const float4*)(C + ((size_t)(bb + crow) * S_ + tstep) * H_ + kc + cc0);
        *(float4*)&cr[0]  = src[0];
        *(float4*)&cr[4]  = src[1];
        *(float4*)&cr[8]  = src[2];
        *(float4*)&cr[12] = src[3];
#pragma unroll
        for (int i = 0; i < 3; ++i) {
            const int gid = i * 256 + t;      // 0..767
            const int row = gid >> 3;         // 0..95
            const int grp = gid & 7;
            const int grow = (row >> 5) * H_ + jb + (row & 31);
            wreg[i] = *(const uint4*)(Wihb + (size_t)grow * H_ + kc + grp * 8);
        }
    };
    auto load_h = [&](int kc) {
#pragma unroll
        for (int i = 0; i < 4; ++i) {
            const int gid  = i * 256 + t;
            const int tile = gid >> 9;        // 0: h_hi, 1: h_lo
            const int rem  = gid & 511;
            const int row  = rem >> 3;
            const int grp  = rem & 7;
            const ushort* src = (tile ? hr_lo : hr_hi) + (size_t)(bb + row) * H_ + kc + grp * 8;
            hreg[i] = *(const uint4*)src;
        }
    };
    auto write_lds = [&]() {
        __align__(16) ushort cb[16];
#pragma unroll
        for (int u = 0; u < 16; ++u) cb[u] = f2bf(cr[u]);
        uint4* d = (uint4*)&As[crow * 72 + cc0];
        d[0] = ((uint4*)cb)[0]; d[1] = ((uint4*)cb)[1];
#pragma unroll
        for (int i = 0; i < 4; ++i) {
            const int gid  = i * 256 + t;
            const int tile = gid >> 9;
            const int rem  = gid & 511;
            const int row  = rem >> 3;
            const int grp  = rem & 7;
            *(uint4*)&As[(1 + tile) * 4608 + row * 72 + grp * 8] = hreg[i];
        }
#pragma unroll
        for (int i = 0; i < 3; ++i) {
            const int gid = i * 256 + t;
            const int row = gid >> 3;
            const int grp = gid & 7;
            *(uint4*)&Wih_s[row * 72 + grp * 8] = wreg[i];
        }
    };

    load_cw(0, 0);
    load_h(0);   // buffer0 zeroed by the prior memset (stream-ordered)

    for (int tstep = 0; tstep < S_; ++tstep) {
        // G prefetch for this step (hides under kc loop)
        float g_[4];
#pragma unroll
        for (int r4 = 0; r4 < 4; ++r4)
            g_[r4] = G[(size_t)(bb + wv * 16 + quad * 4 + r4) * S_ + tstep];

        floatx4 acc_r[2], acc_z[2], acc_xn[2], acc_hn[2];
#pragma unroll
        for (int i = 0; i < 2; ++i) {
            acc_r[i] = (floatx4){0.f,0.f,0.f,0.f}; acc_z[i]  = (floatx4){0.f,0.f,0.f,0.f};
            acc_xn[i]= (floatx4){0.f,0.f,0.f,0.f}; acc_hn[i] = (floatx4){0.f,0.f,0.f,0.f};
        }
        float hold_[2][4];

        for (int kc = 0; kc < H_; kc += 64) {
            write_lds();
            __syncthreads();
            const int kn = kc + 64;
            if (kn < H_) { load_cw(tstep, kn); load_h(kn); }  // hide under MFMA phase
            if (kc == hold_kc) {
                // capture h_old for this block's own j-cols from the staged tile
#pragma unroll
                for (int nt = 0; nt < 2; ++nt)
#pragma unroll
                    for (int r4 = 0; r4 < 4; ++r4) {
                        const int trow = wv * 16 + quad * 4 + r4;
                        const int col  = hold_off + nt * 16 + l15;
                        hold_[nt][r4] = bf2f(As[1 * 4608 + trow * 72 + col]) +
                                        bf2f(As[2 * 4608 + trow * 72 + col]);
                    }
            }
#pragma unroll
            for (int ks = 0; ks < 64; ks += 32) {
                const int ao = ks + quad * 8;
                const bf16x8 a_c  = *(const bf16x8*)&As[0 * 4608 + arow * 72 + ao];
                const bf16x8 a_hh = *(const bf16x8*)&As[1 * 4608 + arow * 72 + ao];
                const bf16x8 a_hl = *(const bf16x8*)&As[2 * 4608 + arow * 72 + ao];
#pragma unroll
                for (int nt = 0; nt < 2; ++nt) {
                    const int jj = nt * 16 + l15;
                    const bf16x8 ih_r = *(const bf16x8*)&Wih_s[(0 * 32 + jj) * 72 + ao];
                    const bf16x8 ih_z = *(const bf16x8*)&Wih_s[(1 * 32 + jj) * 72 + ao];
                    const bf16x8 ih_n = *(const bf16x8*)&Wih_s[(2 * 32 + jj) * 72 + ao];
                    const bf16x8 hh_r = *(const bf16x8*)&Whh_s[(0 * 32 + jj) * 520 + kc + ao];
                    const bf16x8 hh_z = *(const bf16x8*)&Whh_s[(1 * 32 + jj) * 520 + kc + ao];
                    const bf16x8 hh_n = *(const bf16x8*)&Whh_s[(2 * 32 + jj) * 520 + kc + ao];
                    acc_r[nt]  = __builtin_amdgcn_mfma_f32_16x16x32_bf16(a_c,  ih_r, acc_r[nt],  0, 0, 0);
                    acc_r[nt]  = __builtin_amdgcn_mfma_f32_16x16x32_bf16(a_hh, hh_r, acc_r[nt],  0, 0, 0);
                    acc_r[nt]  = __builtin_amdgcn_mfma_f32_16x16x32_bf16(a_hl, hh_r, acc_r[nt],  0, 0, 0);
                    acc_z[nt]  = __builtin_amdgcn_mfma_f32_16x16x32_bf16(a_c,  ih_z, acc_z[nt],  0, 0, 0);
                    acc_z[nt]  = __builtin_amdgcn_mfma_f32_16x16x32_bf16(a_hh, hh_z, acc_z[nt],  0, 0, 0);
                    acc_z[nt]  = __builtin_amdgcn_mfma_f32_16x16x32_bf16(a_hl, hh_z, acc_z[nt],  0, 0, 0);
                    acc_xn[nt] = __builtin_amdgcn_mfma_f32_16x16x32_bf16(a_c,  ih_n, acc_xn[nt], 0, 0, 0);
                    acc_hn[nt] = __builtin_amdgcn_mfma_f32_16x16x32_bf16(a_hh, hh_n, acc_hn[nt], 0, 0, 0);
                    acc_hn[nt] = __builtin_amdgcn_mfma_f32_16x16x32_bf16(a_hl, hh_n, acc_hn[nt], 0, 0, 0);
                }
            }
            __syncthreads();
        }

        // --- epilogue: gates -> h_new ---
        const int last = (tstep == S_ - 1);
#pragma unroll
        for (int nt = 0; nt < 2; ++nt) {
            const int j = jb + nt * 16 + l15;
#pragma unroll
            for (int r4 = 0; r4 < 4; ++r4) {
                const int b = bb + wv * 16 + quad * 4 + r4;
                const size_t idx = (size_t)b * H_ + j;
                const float hold = hold_[nt][r4];
                const float g = g_[r4];
                const float rg = 1.f / (1.f + expf(-(acc_r[nt][r4] + br_[nt])));
                const float zg = 1.f / (1.f + expf(-(acc_z[nt][r4] + bz_[nt])));
                const float ng = tanhf(acc_xn[nt][r4] + bxn_[nt] + rg * (acc_hn[nt][r4] + bhn_[nt]));
                const float hgru = (1.f - zg) * ng + zg * hold;
                const float hnew = g * hgru + (1.f - g) * hold;
                const ushort hb = f2bf(hnew);
                hw_hi[idx] = hb;
                hw_lo[idx] = f2bf(hnew - bf2f(hb));
                if (last) out[idx] = hnew;
            }
        }
        if (last) break;

        // swap read/write buffers
        {
            const ushort* th = hr_hi; const ushort* tl = hr_lo;
            hr_hi = (const ushort*)hw_hi; hr_lo = (const ushort*)hw_lo;
            hw_hi = (ushort*)th; hw_lo = (ushort*)tl;
        }
        // prefetch next step's C / Wih before the barrier (the entry fence drains
        // them, so the data is in registers by barrier exit)
        load_cw(tstep + 1, 0);
        grid_barrier_256(t);    // device-scope fenced grid barrier
        load_h(0);              // h readable only after the barrier
    }
}

extern "C" void kernel_launch(void* const* d_in, const int* in_sizes, int n_in,
                              void* d_out, int out_size, void* d_ws, size_t ws_size,
                              hipStream_t stream) {
    (void)in_sizes; (void)n_in; (void)out_size; (void)ws_size;
    const float* C    = (const float*)d_in[0];
    const float* Q    = (const float*)d_in[1];
    const float* M    = (const float*)d_in[2];
    const float* fc1w = (const float*)d_in[3];
    const float* fc1b = (const float*)d_in[4];
    const float* fc2w = (const float*)d_in[5];
    const float* fc2b = (const float*)d_in[6];
    const float* Wih  = (const float*)d_in[7];
    const float* Whh  = (const float*)d_in[8];
    const float* bih  = (const float*)d_in[9];
    const float* bhh  = (const float*)d_in[10];
    float* out = (float*)d_out;

    char* ws = (char*)d_ws;
    float*  Gbuf  = (float*)ws;                          // 256 KB
    ushort* hhi0  = (ushort*)(ws + 262144);              // 1 MB
    ushort* hlo0  = (ushort*)(ws + 262144 + 1048576);    // 1 MB
    ushort* hhi1  = (ushort*)(ws + 262144 + 2097152);    // 1 MB
    ushort* hlo1  = (ushort*)(ws + 262144 + 3145728);    // 1 MB
    ushort* fc1wb = (ushort*)(ws + 4456448);             // 480 KB
    ushort* Wihb  = (ushort*)(ws + 4947968);             // 1.5 MB
    ushort* Whhb  = (ushort*)(ws + 6520832);             // 1.5 MB (ends ~7.72 MB)

    // h0 = 0: zero buffer 0 (hhi0+hlo0 contiguous; buffer 1 fully written at t=0)
    hipMemsetAsync(hhi0, 0, 2097152, stream);

    prep_w<<<256, 256, 0, stream>>>(fc1w, fc1wb, Wih, Wihb, Whh, Whhb);
    g_kernel<<<B_, 256, 0, stream>>>(C, Q, M, fc1wb, fc1b, fc2w, fc2b, Gbuf);
    scan_all<<<256, 256, 0, stream>>>(C, Wihb, Whhb, bih, bhh, Gbuf,
                                      hhi0, hlo0, hhi1, hlo1, out);
}

// Round 3
// 1482.355 us; speedup vs baseline: 3.7597x; 3.7597x over previous
//
// EpisodicMemory: fp32 inputs/output.
//   prep_w    : one-shot fp32->bf16 conversion of fc1_w, W_ih, W_hh into ws.
//   g_kernel  : per-b block, feat@fc1w^T via 16x16x32 bf16 MFMA (unchanged).
//   scan_all  : R7 — persistent scan with PER-GROUP barriers, no fences.
//               R6's grid barrier cost ~80us/step: per-wave __threadfence at agent
//               scope = buffer_wbl2/inv (full L2 writeback+invalidate) x 1024 waves
//               x 2/step, serializing at TCC. Fix exploits dataflow: batches never
//               mix, so only the 16 j-blocks sharing a b-tile must sync (16
//               independent groups of 16). h exchange uses coherence-point ops:
//               __hip_atomic_store/load(RELAXED, AGENT) = global ops with sc0 sc1
//               (bypass L2, visible once vmcnt retires) -> NO wbl2 at all.
//               h (hi,lo) packed 1 uint32/element, double-buffered in ws.
//               Barrier: single-writer progress slots (member jt stores
//               vbase+t+1 after s_waitcnt vmcnt(0); wave0 lanes poll the 16 slots,
//               __all(v>=target)). vbase = own slot at kernel start (single-writer,
//               monotone, no resets -> replay/graph-safe, causality-proved).
//               Whh LDS-resident; reg prefetch of next-kc C/h/Wih under MFMA;
//               next-step C/Wih prefetched before barrier. 141KB LDS => 1 block/CU.
#include <hip/hip_runtime.h>
#include <hip/hip_bf16.h>

#define H_ 512
#define SH_ 120
#define B_ 1024
#define S_ 64

typedef __bf16 bf16x8 __attribute__((ext_vector_type(8)));
typedef float floatx4 __attribute__((ext_vector_type(4)));

__device__ __forceinline__ float bf2f(ushort u) {
    union { unsigned int i; float f; } v; v.i = ((unsigned int)u) << 16; return v.f;
}
__device__ __forceinline__ ushort f2bf(float f) {
    union { float f; unsigned int i; } v; v.f = f;
    unsigned int x = v.i;
    unsigned int r = (x + 0x7fffu + ((x >> 16) & 1u)) >> 16;  // RNE
    return (ushort)r;
}

// Per-(group, member) progress slots. Group = b-tile (16 blocks), member = j-tile.
// Single writer per slot (member's thread 0), monotone values, never reset:
// run r leaves every slot at 63*r, so vbase (own slot at kernel start) is exact
// and common across the group. 64B per group = 1 cacheline.
__device__ __attribute__((aligned(64))) unsigned g_prog[256];

// ---------------------------------------------------------------------------
// prep_w: one-shot fp32 -> bf16 of the three weight matrices.
// ---------------------------------------------------------------------------
__global__ __launch_bounds__(256) void prep_w(
    const float* __restrict__ fc1w, ushort* __restrict__ fc1wb,
    const float* __restrict__ Wih,  ushort* __restrict__ Wihb,
    const float* __restrict__ Whh,  ushort* __restrict__ Whhb)
{
    const int stride = gridDim.x * blockDim.x;
    const int tid = blockIdx.x * blockDim.x + threadIdx.x;
    for (int i = tid; i < 61440; i += stride) {            // 120*2048/4
        const float4 v = ((const float4*)fc1w)[i];
        ushort4 o; o.x = f2bf(v.x); o.y = f2bf(v.y); o.z = f2bf(v.z); o.w = f2bf(v.w);
        ((ushort4*)fc1wb)[i] = o;
    }
    for (int i = tid; i < 196608; i += stride) {           // 1536*512/4
        const float4 v = ((const float4*)Wih)[i];
        ushort4 o; o.x = f2bf(v.x); o.y = f2bf(v.y); o.z = f2bf(v.z); o.w = f2bf(v.w);
        ((ushort4*)Wihb)[i] = o;
    }
    for (int i = tid; i < 196608; i += stride) {
        const float4 v = ((const float4*)Whh)[i];
        ushort4 o; o.x = f2bf(v.x); o.y = f2bf(v.y); o.z = f2bf(v.z); o.w = f2bf(v.w);
        ((ushort4*)Whhb)[i] = o;
    }
}

// ---------------------------------------------------------------------------
// G kernel: one block per b. Computes G[b, s] for s=0..63. (unchanged)
// ---------------------------------------------------------------------------
__global__ __launch_bounds__(256) void g_kernel(
    const float* __restrict__ C, const float* __restrict__ Q,
    const float* __restrict__ M, const ushort* __restrict__ fc1wb,
    const float* __restrict__ fc1b, const float* __restrict__ fc2w,
    const float* __restrict__ fc2b, float* __restrict__ G)
{
    __shared__ float qrow[H_];
    __shared__ float mrow[H_];
    __shared__ __align__(16) ushort featT[64 * 72];   // 64 s-rows x 64 k (stride 72)
    __shared__ __align__(16) ushort wT[128 * 72];     // 128 n-rows x 64 k (rows>=120 zero)
    __shared__ float h1s[64 * 132];                   // 64 x 128 fp32 (stride 132)

    const int b = blockIdx.x;
    const int t = threadIdx.x;
    for (int i = t; i < H_; i += 256) { qrow[i] = Q[(size_t)b * H_ + i]; mrow[i] = M[(size_t)b * H_ + i]; }

    const int wrow = t >> 1;
    const int wc0  = (t & 1) * 32;
    if (wrow >= SH_) {              // zero-fill dead wT rows once
        uint4* dst = (uint4*)&wT[wrow * 72 + wc0];
        const uint4 z = {0u, 0u, 0u, 0u};
        dst[0] = z; dst[1] = z; dst[2] = z; dst[3] = z;
    }
    __syncthreads();

    const int lane = t & 63;
    const int wv   = t >> 6;
    const int quad = lane >> 4;
    const int l15  = lane & 15;
    const int arow = wv * 16 + l15;
    const int s    = t >> 2;
    const int c0   = (t & 3) * 16;

    floatx4 acc[8];
#pragma unroll
    for (int i = 0; i < 8; ++i) acc[i] = (floatx4){0.f, 0.f, 0.f, 0.f};

    for (int hc = 0; hc < H_; hc += 64) {
        float cr[16];
        {
            const float4* csrc = (const float4*)(C + ((size_t)b * S_ + s) * H_ + hc + c0);
            *(float4*)&cr[0]  = csrc[0];
            *(float4*)&cr[4]  = csrc[1];
            *(float4*)&cr[8]  = csrc[2];
            *(float4*)&cr[12] = csrc[3];
        }
#pragma unroll
        for (int seg = 0; seg < 4; ++seg) {
#pragma unroll
            for (int u = 0; u < 16; ++u) {
                const int kk = c0 + u;
                const float c = cr[u];
                const float o = (seg == 0 || seg == 2) ? qrow[hc + kk] : mrow[hc + kk];
                const float v = (seg < 2) ? c * o : fabsf(c - o);
                featT[s * 72 + kk] = f2bf(v);
            }
            if (wrow < SH_) {
                const uint4* src = (const uint4*)(fc1wb + (size_t)wrow * (4 * H_) + seg * H_ + hc + wc0);
                uint4* dst = (uint4*)&wT[wrow * 72 + wc0];
                dst[0] = src[0]; dst[1] = src[1]; dst[2] = src[2]; dst[3] = src[3];
            }
            __syncthreads();
#pragma unroll
            for (int ks = 0; ks < 64; ks += 32) {
                const int ao = ks + quad * 8;
                const bf16x8 af = *(const bf16x8*)&featT[arow * 72 + ao];
#pragma unroll
                for (int nt = 0; nt < 8; ++nt) {
                    const bf16x8 bfr = *(const bf16x8*)&wT[(nt * 16 + l15) * 72 + ao];
                    acc[nt] = __builtin_amdgcn_mfma_f32_16x16x32_bf16(af, bfr, acc[nt], 0, 0, 0);
                }
            }
            __syncthreads();
        }
    }

#pragma unroll
    for (int nt = 0; nt < 8; ++nt) {
        const int col = nt * 16 + l15;
        const float bias = (col < SH_) ? fc1b[col] : 0.f;
#pragma unroll
        for (int r = 0; r < 4; ++r) {
            const int row = wv * 16 + quad * 4 + r;
            h1s[row * 132 + col] = (col < SH_) ? tanhf(acc[nt][r] + bias) : 0.f;
        }
    }
    __syncthreads();
    {
        const int part = t & 3;
        float sum = 0.f;
        for (int k = part; k < SH_; k += 4) sum += h1s[s * 132 + k] * fc2w[k];
        sum += __shfl_xor(sum, 1);
        sum += __shfl_xor(sum, 2);
        if (part == 0) {
            const float logit = sum + fc2b[0];
            G[(size_t)b * S_ + s] = 1.f / (1.f + expf(-logit));
        }
    }
}

// ---------------------------------------------------------------------------
// scan_all: persistent scan, normal launch. 256 blocks x 256 threads, 1 block/CU
// (forced by 141 KB LDS). Block = (j-tile 32 cols) x (b-tile 64 batches). Whh
// slice lives in LDS for all 64 steps. Per-b-tile 16-block barrier between steps;
// h packed (hi<<16|lo) per element, double-buffered, exchanged via sc0sc1 ops.
// ---------------------------------------------------------------------------
__global__ __launch_bounds__(256) void scan_all(
    const float* __restrict__ C, const ushort* __restrict__ Wihb,
    const ushort* __restrict__ Whhb, const float* __restrict__ bih,
    const float* __restrict__ bhh, const float* __restrict__ G,
    uint* __restrict__ hp0, uint* __restrict__ hp1,
    float* __restrict__ out)
{
    __shared__ __align__(16) ushort Whh_s[96 * 520];   // 99840 B, persistent
    __shared__ __align__(16) ushort As[3 * 64 * 72];   // c | h_hi | h_lo  27648 B
    __shared__ __align__(16) ushort Wih_s[96 * 72];    // per-kc staging   13824 B

    const int bx = blockIdx.x;
    // XCD map heuristic: blocks sharing a b-tile land on one XCD (bx%8 equal) ->
    // C/h locality. Correctness does NOT depend on it (sc0sc1 h exchange).
    const int jt = bx >> 4;
    const int bt = ((bx & 7) << 1) | ((bx >> 3) & 1);
    const int jb = jt * 32;
    const int bb = bt * 64;
    const int t  = threadIdx.x;
    const int lane = t & 63;
    const int wv   = t >> 6;
    const int quad = lane >> 4;
    const int l15  = lane & 15;
    const int arow = wv * 16 + l15;
    const int crow = t >> 2;
    const int cc0  = (t & 3) * 16;
    const int hrow = t >> 2;          // h staging: 1 row x 16 j-elements per thread
    const int hseg = t & 3;

    // --- barrier base: own slot, single-writer => exact, race-free ---
    const unsigned vbase = __hip_atomic_load(&g_prog[(bt << 4) + jt],
                                             __ATOMIC_RELAXED, __HIP_MEMORY_SCOPE_AGENT);

    // --- one-time: Whh slice (3 gates x 32 j-cols, full K) into LDS ---
#pragma unroll
    for (int i = 0; i < 24; ++i) {
        const int gid = i * 256 + t;          // 0..6143
        const int row = gid >> 6;             // 0..95
        const int grp = gid & 63;             // 0..63 (8-elem groups)
        const int grow = (row >> 5) * H_ + jb + (row & 31);
        *(uint4*)&Whh_s[row * 520 + grp * 8] =
            *(const uint4*)(Whhb + (size_t)grow * H_ + grp * 8);
    }

    // --- hoisted biases (constant across t) ---
    float br_[2], bz_[2], bxn_[2], bhn_[2];
#pragma unroll
    for (int nt = 0; nt < 2; ++nt) {
        const int j = jb + nt * 16 + l15;
        br_[nt]  = bih[j] + bhh[j];
        bz_[nt]  = bih[H_ + j] + bhh[H_ + j];
        bxn_[nt] = bih[2 * H_ + j];
        bhn_[nt] = bhh[2 * H_ + j];
    }

    const int hold_kc  = (jb >> 6) << 6;   // kc chunk containing this block's j cols
    const int hold_off = jb & 63;

    const uint* hr = hp0;   // read buffer (packed h)
    uint*       hw = hp1;   // write buffer

    // --- prefetch registers ---
    float cr[16];
    unsigned long long hreg[8];
    uint4 wreg[3];

    auto load_cw = [&](int tstep, int kc) {
        const float4* src = (const float4*)(C + ((size_t)(bb + crow) * S_ + tstep) * H_ + kc + cc0);
        *(float4*)&cr[0]  = src[0];
        *(float4*)&cr[4]  = src[1];
        *(float4*)&cr[8]  = src[2];
        *(float4*)&cr[12] = src[3];
#pragma unroll
        for (int i = 0; i < 3; ++i) {
            const int gid = i * 256 + t;      // 0..767
            const int row = gid >> 3;         // 0..95
            const int grp = gid & 7;
            const int grow = (row >> 5) * H_ + jb + (row & 31);
            wreg[i] = *(const uint4*)(Wihb + (size_t)grow * H_ + kc + grp * 8);
        }
    };
    auto load_h = [&](int kc) {
        // 16 packed elements per thread: row hrow, j = kc + hseg*16 .. +15
        const unsigned long long* src = (const unsigned long long*)
            (hr + (size_t)(bb + hrow) * H_ + kc + hseg * 16);
#pragma unroll
        for (int i = 0; i < 8; ++i)
            hreg[i] = __hip_atomic_load(src + i, __ATOMIC_RELAXED, __HIP_MEMORY_SCOPE_AGENT);
    };
    auto write_lds = [&]() {
        __align__(16) ushort cb[16];
#pragma unroll
        for (int u = 0; u < 16; ++u) cb[u] = f2bf(cr[u]);
        uint4* d = (uint4*)&As[crow * 72 + cc0];
        d[0] = ((uint4*)cb)[0]; d[1] = ((uint4*)cb)[1];
        // unpack packed h -> hi plane / lo plane
        uint hiu[8], lou[8];
#pragma unroll
        for (int i = 0; i < 8; ++i) {
            const uint p0 = (uint)(hreg[i] & 0xFFFFFFFFull);
            const uint p1 = (uint)(hreg[i] >> 32);
            hiu[i] = (p0 >> 16) | (p1 & 0xFFFF0000u);
            lou[i] = (p0 & 0xFFFFu) | (p1 << 16);
        }
        uint4* dh = (uint4*)&As[1 * 4608 + hrow * 72 + hseg * 16];
        dh[0] = *(uint4*)&hiu[0]; dh[1] = *(uint4*)&hiu[4];
        uint4* dl = (uint4*)&As[2 * 4608 + hrow * 72 + hseg * 16];
        dl[0] = *(uint4*)&lou[0]; dl[1] = *(uint4*)&lou[4];
#pragma unroll
        for (int i = 0; i < 3; ++i) {
            const int gid = i * 256 + t;
            const int row = gid >> 3;
            const int grp = gid & 7;
            *(uint4*)&Wih_s[row * 72 + grp * 8] = wreg[i];
        }
    };

    load_cw(0, 0);
    load_h(0);   // buffer0 zeroed by the prior memset (stream-ordered)

    for (int tstep = 0; tstep < S_; ++tstep) {
        // G for this step (L2-hot, 256 KB)
        float g_[4];
#pragma unroll
        for (int r4 = 0; r4 < 4; ++r4)
            g_[r4] = G[(size_t)(bb + wv * 16 + quad * 4 + r4) * S_ + tstep];

        floatx4 acc_r[2], acc_z[2], acc_xn[2], acc_hn[2];
#pragma unroll
        for (int i = 0; i < 2; ++i) {
            acc_r[i] = (floatx4){0.f,0.f,0.f,0.f}; acc_z[i]  = (floatx4){0.f,0.f,0.f,0.f};
            acc_xn[i]= (floatx4){0.f,0.f,0.f,0.f}; acc_hn[i] = (floatx4){0.f,0.f,0.f,0.f};
        }
        float hold_[2][4];

        for (int kc = 0; kc < H_; kc += 64) {
            write_lds();
            __syncthreads();
            const int kn = kc + 64;
            if (kn < H_) { load_cw(tstep, kn); load_h(kn); }  // hide under MFMA phase
            if (kc == hold_kc) {
                // capture h_old for this block's own j-cols from the staged tile
#pragma unroll
                for (int nt = 0; nt < 2; ++nt)
#pragma unroll
                    for (int r4 = 0; r4 < 4; ++r4) {
                        const int trow = wv * 16 + quad * 4 + r4;
                        const int col  = hold_off + nt * 16 + l15;
                        hold_[nt][r4] = bf2f(As[1 * 4608 + trow * 72 + col]) +
                                        bf2f(As[2 * 4608 + trow * 72 + col]);
                    }
            }
#pragma unroll
            for (int ks = 0; ks < 64; ks += 32) {
                const int ao = ks + quad * 8;
                const bf16x8 a_c  = *(const bf16x8*)&As[0 * 4608 + arow * 72 + ao];
                const bf16x8 a_hh = *(const bf16x8*)&As[1 * 4608 + arow * 72 + ao];
                const bf16x8 a_hl = *(const bf16x8*)&As[2 * 4608 + arow * 72 + ao];
#pragma unroll
                for (int nt = 0; nt < 2; ++nt) {
                    const int jj = nt * 16 + l15;
                    const bf16x8 ih_r = *(const bf16x8*)&Wih_s[(0 * 32 + jj) * 72 + ao];
                    const bf16x8 ih_z = *(const bf16x8*)&Wih_s[(1 * 32 + jj) * 72 + ao];
                    const bf16x8 ih_n = *(const bf16x8*)&Wih_s[(2 * 32 + jj) * 72 + ao];
                    const bf16x8 hh_r = *(const bf16x8*)&Whh_s[(0 * 32 + jj) * 520 + kc + ao];
                    const bf16x8 hh_z = *(const bf16x8*)&Whh_s[(1 * 32 + jj) * 520 + kc + ao];
                    const bf16x8 hh_n = *(const bf16x8*)&Whh_s[(2 * 32 + jj) * 520 + kc + ao];
                    acc_r[nt]  = __builtin_amdgcn_mfma_f32_16x16x32_bf16(a_c,  ih_r, acc_r[nt],  0, 0, 0);
                    acc_r[nt]  = __builtin_amdgcn_mfma_f32_16x16x32_bf16(a_hh, hh_r, acc_r[nt],  0, 0, 0);
                    acc_r[nt]  = __builtin_amdgcn_mfma_f32_16x16x32_bf16(a_hl, hh_r, acc_r[nt],  0, 0, 0);
                    acc_z[nt]  = __builtin_amdgcn_mfma_f32_16x16x32_bf16(a_c,  ih_z, acc_z[nt],  0, 0, 0);
                    acc_z[nt]  = __builtin_amdgcn_mfma_f32_16x16x32_bf16(a_hh, hh_z, acc_z[nt],  0, 0, 0);
                    acc_z[nt]  = __builtin_amdgcn_mfma_f32_16x16x32_bf16(a_hl, hh_z, acc_z[nt],  0, 0, 0);
                    acc_xn[nt] = __builtin_amdgcn_mfma_f32_16x16x32_bf16(a_c,  ih_n, acc_xn[nt], 0, 0, 0);
                    acc_hn[nt] = __builtin_amdgcn_mfma_f32_16x16x32_bf16(a_hh, hh_n, acc_hn[nt], 0, 0, 0);
                    acc_hn[nt] = __builtin_amdgcn_mfma_f32_16x16x32_bf16(a_hl, hh_n, acc_hn[nt], 0, 0, 0);
                }
            }
            __syncthreads();
        }

        // --- epilogue: gates -> h_new, write-through packed (visible at IF) ---
        const int last = (tstep == S_ - 1);
#pragma unroll
        for (int nt = 0; nt < 2; ++nt) {
            const int j = jb + nt * 16 + l15;
#pragma unroll
            for (int r4 = 0; r4 < 4; ++r4) {
                const int b = bb + wv * 16 + quad * 4 + r4;
                const size_t idx = (size_t)b * H_ + j;
                const float hold = hold_[nt][r4];
                const float g = g_[r4];
                const float rg = 1.f / (1.f + expf(-(acc_r[nt][r4] + br_[nt])));
                const float zg = 1.f / (1.f + expf(-(acc_z[nt][r4] + bz_[nt])));
                const float ng = tanhf(acc_xn[nt][r4] + bxn_[nt] + rg * (acc_hn[nt][r4] + bhn_[nt]));
                const float hgru = (1.f - zg) * ng + zg * hold;
                const float hnew = g * hgru + (1.f - g) * hold;
                const ushort hb = f2bf(hnew);
                const ushort hl = f2bf(hnew - bf2f(hb));
                __hip_atomic_store(&hw[idx], ((uint)hb << 16) | (uint)hl,
                                   __ATOMIC_RELAXED, __HIP_MEMORY_SCOPE_AGENT);
                if (last) out[idx] = hnew;
            }
        }
        if (last) break;

        // swap read/write buffers
        {
            uint* tmp = hw; hw = (uint*)hr; hr = (const uint*)tmp;
        }
        // prefetch next step's C / Wih before the barrier (drained by the waitcnt,
        // so the data is in registers by barrier exit)
        load_cw(tstep + 1, 0);

        // --- per-b-tile barrier: 16 blocks, no fences ---
        asm volatile("s_waitcnt vmcnt(0)" ::: "memory");   // h stores at coherence pt
        __syncthreads();
        if (t == 0)
            __hip_atomic_store(&g_prog[(bt << 4) + jt], vbase + (unsigned)(tstep + 1),
                               __ATOMIC_RELAXED, __HIP_MEMORY_SCOPE_AGENT);
        if (wv == 0) {
            const unsigned tgt = vbase + (unsigned)(tstep + 1);
            const int slot = (bt << 4) + (t & 15);   // 4 lanes per member, covers all 16
            while (true) {
                const unsigned v = __hip_atomic_load(&g_prog[slot],
                                                     __ATOMIC_RELAXED, __HIP_MEMORY_SCOPE_AGENT);
                if (__all(v >= tgt)) break;
                __builtin_amdgcn_s_sleep(4);
            }
        }
        __syncthreads();
        load_h(0);              // h(t+1 inputs) readable only after the barrier
    }
}

extern "C" void kernel_launch(void* const* d_in, const int* in_sizes, int n_in,
                              void* d_out, int out_size, void* d_ws, size_t ws_size,
                              hipStream_t stream) {
    (void)in_sizes; (void)n_in; (void)out_size; (void)ws_size;
    const float* C    = (const float*)d_in[0];
    const float* Q    = (const float*)d_in[1];
    const float* M    = (const float*)d_in[2];
    const float* fc1w = (const float*)d_in[3];
    const float* fc1b = (const float*)d_in[4];
    const float* fc2w = (const float*)d_in[5];
    const float* fc2b = (const float*)d_in[6];
    const float* Wih  = (const float*)d_in[7];
    const float* Whh  = (const float*)d_in[8];
    const float* bih  = (const float*)d_in[9];
    const float* bhh  = (const float*)d_in[10];
    float* out = (float*)d_out;

    char* ws = (char*)d_ws;
    float* Gbuf  = (float*)ws;                           // 256 KB
    uint*  hp0   = (uint*)(ws + 262144);                 // 2 MB (packed h, buf 0)
    uint*  hp1   = (uint*)(ws + 262144 + 2097152);       // 2 MB (packed h, buf 1)
    ushort* fc1wb = (ushort*)(ws + 4456448);             // 480 KB
    ushort* Wihb  = (ushort*)(ws + 4947968);             // 1.5 MB
    ushort* Whhb  = (ushort*)(ws + 6520832);             // 1.5 MB (ends ~7.72 MB)

    // h0 = 0: zero packed buffer 0 (buffer 1 fully written at t=0)
    hipMemsetAsync(hp0, 0, 2097152, stream);

    prep_w<<<256, 256, 0, stream>>>(fc1w, fc1wb, Wih, Wihb, Whh, Whhb);
    g_kernel<<<B_, 256, 0, stream>>>(C, Q, M, fc1wb, fc1b, fc2w, fc2b, Gbuf);
    scan_all<<<256, 256, 0, stream>>>(C, Wihb, Whhb, bih, bhh, Gbuf,
                                      hp0, hp1, out);
}